// Round 1
// baseline (596.578 us; speedup 1.0000x reference)
//
#include <hip/hip_runtime.h>
#include <stdint.h>

#define TT 96
#define SS 1024
#define BB 256
#define START_TAG 94
#define STOP_TAG 95
#define CH 16            // time-steps per staged feature chunk
#define NTH 384          // 96 j-columns x 4 i-quarters
#define LOG2E 1.44269504088896340736f
#define LN2   0.69314718055994530942f

// ws: E2T[j*96 + i] = exp(trans[i][j])  (transposed exp-table, 36 KB)
__global__ void prep_kernel(const float* __restrict__ trans, float* __restrict__ E2T) {
    int idx = blockIdx.x * blockDim.x + threadIdx.x;
    if (idx < TT * TT) {
        int jj = idx / TT, ii = idx % TT;
        E2T[idx] = expf(trans[ii * TT + jj]);
    }
}

__global__ __launch_bounds__(NTH) void forward_kernel(
    const float* __restrict__ features, const int* __restrict__ mask,
    const float* __restrict__ trans, const float* __restrict__ E2T,
    float* __restrict__ out)
{
    const int b    = blockIdx.x;
    const int tid  = threadIdx.x;
    const int j    = tid >> 2;      // output tag column 0..95
    const int q    = tid & 3;       // i-quarter 0..3
    const int lane = tid & 63;
    const int wv   = tid >> 6;      // wave id 0..5

    __shared__ float alpha[2][TT];      // double-buffered scaled forward vars
    __shared__ float fch[2][CH * TT];   // double-buffered feature chunks (2x6KB)
    __shared__ float wred[6];
    __shared__ int   wcnt[6];
    __shared__ int   len_sh;

    // ---- sequence length from prefix mask ----
    int cnt = 0;
    for (int i = tid; i < SS; i += NTH) cnt += (mask[b * SS + i] != 0);
    #pragma unroll
    for (int d = 1; d < 64; d <<= 1) cnt += __shfl_xor(cnt, d);
    if (lane == 0) wcnt[wv] = cnt;
    __syncthreads();
    if (tid == 0) {
        int L = 0;
        for (int w = 0; w < 6; ++w) L += wcnt[w];
        len_sh = L;
    }

    // ---- E column-slice into registers: Er[k] = exp(trans[q*24+k][j]) ----
    float Er[24];
    {
        const float4* ep = reinterpret_cast<const float4*>(E2T + j * TT + q * 24);
        #pragma unroll
        for (int k = 0; k < 6; ++k) {
            float4 e4 = ep[k];
            Er[4*k+0] = e4.x; Er[4*k+1] = e4.y; Er[4*k+2] = e4.z; Er[4*k+3] = e4.w;
        }
    }

    // ---- prologue: stage chunk 0, issue chunk 1 ----
    const float* fb = features + (size_t)b * SS * TT;
    float4 r0    = reinterpret_cast<const float4*>(fb)[tid];
    float4 rnext = reinterpret_cast<const float4*>(fb + CH * TT)[tid];
    reinterpret_cast<float4*>(&fch[0][0])[tid] = r0;
    __syncthreads();
    const int len = len_sh;

    // ---- t = 0 init: alpha = exp(f0 + trans[START,:]) ----
    if (q == 0) {
        float p0 = fch[0][j] + trans[START_TAG * TT + j];
        alpha[0][j] = exp2f(p0 * LOG2E);
    }
    __syncthreads();

    float c2 = 0.0f;          // accumulated log2 scale (block-uniform)
    float pending = 1.0f;     // 2^-pe scale to apply at next step
    int   pe = 0;

    const int clast = (len - 1) >> 4;
    for (int c = 0; c <= clast; ++c) {
        if (c > 0) {
            // write staged chunk c, issue load of chunk c+1 (clamped in-row)
            reinterpret_cast<float4*>(&fch[c & 1][0])[tid] = rnext;
            int cn = c + 1; if (cn > SS / CH - 1) cn = SS / CH - 1;
            rnext = reinterpret_cast<const float4*>(fb + cn * CH * TT)[tid];
            __syncthreads();
        }
        const int t0   = c * CH;
        const int tbeg = (c == 0) ? 1 : t0;
        int tend = t0 + CH; if (tend > len) tend = len;

        for (int t = tbeg; t < tend; ++t) {
            const float* acur = alpha[(t + 1) & 1];   // alpha at time t-1
            const float4* ap = reinterpret_cast<const float4*>(acur + q * 24);
            float sum = 0.0f;
            #pragma unroll
            for (int k = 0; k < 6; ++k) {
                float4 a = ap[k];
                sum = fmaf(Er[4*k+0], a.x, sum);
                sum = fmaf(Er[4*k+1], a.y, sum);
                sum = fmaf(Er[4*k+2], a.z, sum);
                sum = fmaf(Er[4*k+3], a.w, sum);
            }
            // combine i-quarters within the 4-lane quad
            sum += __shfl_xor(sum, 1);
            sum += __shfl_xor(sum, 2);

            float f    = fch[c & 1][(t - t0) * TT + j];
            float anew = sum * exp2f(f * LOG2E) * pending;
            c2 += (float)pe; pe = 0; pending = 1.0f;   // scale now applied

            if (q == 0) alpha[t & 1][j] = anew;
            if ((t & 3) == 3) {
                // block max of anew -> exact power-of-2 renorm for next step
                float m = anew;
                m = fmaxf(m, __shfl_xor(m, 4));
                m = fmaxf(m, __shfl_xor(m, 8));
                m = fmaxf(m, __shfl_xor(m, 16));
                m = fmaxf(m, __shfl_xor(m, 32));
                if (lane == 0) wred[wv] = m;
            }
            __syncthreads();
            if ((t & 3) == 3) {
                float mv = wred[0];
                #pragma unroll
                for (int w = 1; w < 6; ++w) mv = fmaxf(mv, wred[w]);
                int eb  = (int)((__float_as_uint(mv) >> 23) & 255u);
                pe      = eb - 127;
                pending = __uint_as_float((uint32_t)(254 - eb) << 23);
            }
        }
    }

    // ---- logZ_b = ln2 * (c2 + log2( sum_i alpha_i * exp(trans[i,STOP]) )) ----
    float v = 0.0f;
    if (q == 0) v = alpha[(len - 1) & 1][j] * E2T[STOP_TAG * TT + j];
    #pragma unroll
    for (int d = 1; d < 64; d <<= 1) v += __shfl_xor(v, d);
    __syncthreads();
    if (lane == 0) wred[wv] = v;
    __syncthreads();
    if (tid == 0) {
        float tot = 0.0f;
        for (int w = 0; w < 6; ++w) tot += wred[w];
        float logZ = LN2 * (c2 + log2f(tot));
        atomicAdd(out, logZ);
    }
}

__global__ void gold_kernel(const float* __restrict__ features, const int* __restrict__ mask,
                            const int* __restrict__ y, const float* __restrict__ trans,
                            float* __restrict__ out)
{
    int idx = blockIdx.x * blockDim.x + threadIdx.x;
    float e = 0.0f;
    if (idx < BB * SS) {
        int b = idx / SS, t = idx % SS;
        (void)b;
        if (mask[idx] != 0) {
            int yt   = y[idx];
            int prev = (t == 0) ? START_TAG : y[idx - 1];
            e = features[(size_t)idx * TT + yt] + trans[prev * TT + yt];
            bool is_last = (t == SS - 1) || (mask[idx + 1] == 0);
            if (is_last) e += trans[yt * TT + STOP_TAG];
        }
    }
    #pragma unroll
    for (int d = 1; d < 64; d <<= 1) e += __shfl_xor(e, d);
    __shared__ float ws4[4];
    int lane = threadIdx.x & 63, wv = threadIdx.x >> 6;
    if (lane == 0) ws4[wv] = e;
    __syncthreads();
    if (threadIdx.x == 0) {
        float s = ws4[0] + ws4[1] + ws4[2] + ws4[3];
        atomicAdd(out, -s);
    }
}

extern "C" void kernel_launch(void* const* d_in, const int* in_sizes, int n_in,
                              void* d_out, int out_size, void* d_ws, size_t ws_size,
                              hipStream_t stream) {
    const float* features = (const float*)d_in[0];
    const int*   mask     = (const int*)d_in[1];
    const int*   y        = (const int*)d_in[2];
    const float* trans    = (const float*)d_in[3];
    float*       out      = (float*)d_out;
    float*       E2T      = (float*)d_ws;   // 96*96 floats = 36 KB

    hipMemsetAsync(d_out, 0, sizeof(float) * out_size, stream);
    prep_kernel<<<(TT * TT + 255) / 256, 256, 0, stream>>>(trans, E2T);
    forward_kernel<<<BB, NTH, 0, stream>>>(features, mask, trans, E2T, out);
    gold_kernel<<<(BB * SS) / 256, 256, 0, stream>>>(features, mask, y, trans, out);
}